// Round 1
// baseline (517.394 us; speedup 1.0000x reference)
//
#include <hip/hip_runtime.h>
#include <stdint.h>

// ---------------------------------------------------------------------------
// DataEmbedding_ALLPE_Weighted on MI355X (gfx950)
// B=16, L=4096, C=32, D=512, W=24, lags {3,5,7}.  N_tok = 65536.
// Pipeline:
//   feat:      x -> comb[65536,256] bf16  (rolling mean/max/min/std + lags)
//   gemm_conv: h = comb3 @ W1^T + conv_b  (circular shift handled in A-staging)
//   ln_rows:   ce = LN(h; g_c,b_c)  bf16
//   gemm_bt:   Wf = M1 @ tproj_w            (512x512x512, tiny)
//   gemm_bt:   c  = tape_pos @ M2^T + bias2 (4096x512x512, tiny)
//   gemm_bt:   pre = ce @ Wf^T + c[l]       (the fused tok->mixer GEMM)
//   pe_tables: pf = LN(sinusoidal), pl = LN(learned_pe)  per-l tables, bf16
//   final:     out = w0*ce + w1*pf[l] + w2*pl[l] + w3*LN(pre; g_t,b_t)  fp32
// GEMMs: m97-style 128x128 tile, BK=64, global_load_lds width=16,
// mfma_f32_16x16x32_bf16 (verified frag mapping m89/m91).
// ---------------------------------------------------------------------------

typedef unsigned short u16;
using short8  = __attribute__((ext_vector_type(8))) short;
using floatx4 = __attribute__((ext_vector_type(4))) float;
typedef __attribute__((address_space(1))) const unsigned int u32_as1;
typedef __attribute__((address_space(3))) unsigned int       u32_as3;

static __device__ __forceinline__ u16 f2b(float f) {
  unsigned u = __float_as_uint(f);
  u += 0x7FFFu + ((u >> 16) & 1u);          // RNE
  return (u16)(u >> 16);
}
static __device__ __forceinline__ float b2f(u16 h) {
  return __uint_as_float(((unsigned)h) << 16);
}

// ---------------------------------------------------------------- prep mats
// W1[d, j*256+i] = conv_w[d, i, j]; A_m1 = mixer_w[:, :512]; M2t = mixer_w[:,512:];
// tprojT[q, r] = tproj_w[r, q]; tape_bf = bf16(tape_pos[:4096])
__global__ __launch_bounds__(256) void prep_mats(
    const float* __restrict__ conv_w, const float* __restrict__ mixer_w,
    const float* __restrict__ tproj_w, const float* __restrict__ tape_pos,
    u16* __restrict__ W1, u16* __restrict__ A_m1, u16* __restrict__ M2t,
    u16* __restrict__ tprojT, u16* __restrict__ tape_bf) {
  int i = blockIdx.x * 256 + threadIdx.x;
  if (i < 393216) {                                    // W1: 512*768
    int d = i / 768, rem = i - d * 768;
    int j = rem >> 8, c = rem & 255;
    W1[i] = f2b(conv_w[(d * 256 + c) * 3 + j]);
  } else if (i < 393216 + 262144) {
    int k = i - 393216; int p = k >> 9, r = k & 511;
    A_m1[k] = f2b(mixer_w[p * 1024 + r]);
  } else if (i < 393216 + 524288) {
    int k = i - 393216 - 262144; int p = k >> 9, r = k & 511;
    M2t[k] = f2b(mixer_w[p * 1024 + 512 + r]);
  } else if (i < 393216 + 786432) {
    int k = i - 393216 - 524288; int q = k >> 9, r = k & 511;
    tprojT[k] = f2b(tproj_w[r * 512 + q]);
  } else if (i < 393216 + 786432 + 2097152) {
    int k = i - 393216 - 786432;
    tape_bf[k] = f2b(tape_pos[k]);
  }
}

// bias2[p] = sum_r mixer_w[p,r]*tproj_b[r] + mixer_b[p]
__global__ __launch_bounds__(256) void bias2_k(
    const float* __restrict__ mixer_w, const float* __restrict__ tproj_b,
    const float* __restrict__ mixer_b, float* __restrict__ bias2) {
  int p = blockIdx.x * 256 + threadIdx.x;
  if (p < 512) {
    float s = mixer_b[p];
    for (int r = 0; r < 512; ++r) s += mixer_w[p * 1024 + r] * tproj_b[r];
    bias2[p] = s;
  }
}

// -------------------------------------------------------------- features
// grid (64, 16): blockIdx.x = l-tile of 64, blockIdx.y = b. 256 thr.
__global__ __launch_bounds__(256) void feat_kernel(
    const float* __restrict__ x, u16* __restrict__ comb) {
  __shared__ float sx[87 * 32];                 // rows l0-23 .. l0+63
  const int b = blockIdx.y, l0 = blockIdx.x * 64;
  for (int idx = threadIdx.x; idx < 87 * 32; idx += 256) {
    int r = idx >> 5, c = idx & 31;
    int ls = l0 - 23 + r; if (ls < 0) ls = 0;   // replicate pad
    sx[idx] = x[((size_t)b * 4096 + ls) * 32 + c];
  }
  __syncthreads();
  const int c = threadIdx.x & 31, lr0 = threadIdx.x >> 5;
  for (int pass = 0; pass < 8; ++pass) {
    int lr = pass * 8 + lr0;                    // 0..63
    int l = l0 + lr;
    float w[24];
    float s = 0.f, mx = -3.4e38f, mn = 3.4e38f;
    #pragma unroll
    for (int i = 0; i < 24; ++i) {
      float v = sx[(lr + i) * 32 + c];          // window x[l-23..l]
      w[i] = v; s += v; mx = fmaxf(mx, v); mn = fminf(mn, v);
    }
    float mean = s * (1.f / 24.f);
    float ssd = 0.f;
    #pragma unroll
    for (int i = 0; i < 24; ++i) { float d = w[i] - mean; ssd += d * d; }
    float sd = sqrtf(fmaxf(ssd, 0.f) * (1.f / 23.f));   // unbiased, W-1=23
    float xv = w[23];
    float lag3 = xv - sx[(lr + 20) * 32 + c];
    float lag5 = xv - sx[(lr + 18) * 32 + c];
    float lag7 = xv - sx[(lr + 16) * 32 + c];
    size_t base = ((size_t)b * 4096 + l) * 256 + c;
    comb[base +   0] = f2b(xv);
    comb[base +  32] = f2b(mean);
    comb[base +  64] = f2b(mx);
    comb[base +  96] = f2b(mn);
    comb[base + 128] = f2b(sd);
    comb[base + 160] = f2b(lag3);
    comb[base + 192] = f2b(lag5);
    comb[base + 224] = f2b(lag7);
  }
}

// ------------------------------------------------------- generic bf16 GEMM
// C[m,n] = sum_k A[m,k]*Bt[n,k] (+bias[n]) (+rowAdd[(m&rowMask)*512+n])
// out bf16 or fp32.  grid (M/128, N/128), 256 thr.
__global__ __launch_bounds__(256) void gemm_bt(
    const u16* __restrict__ A, const u16* __restrict__ Bt,
    void* __restrict__ outp, int K, int ldc,
    const float* __restrict__ bias, const float* __restrict__ rowAdd,
    int rowMask, int outBf16) {
  __shared__ __align__(16) u16 lA[128 * 64];
  __shared__ __align__(16) u16 lB[128 * 64];
  const int tid = threadIdx.x;
  const int m0 = blockIdx.x * 128, n0 = blockIdx.y * 128;
  const int wave = tid >> 6, lane = tid & 63;
  const int wm = (wave & 1) * 64, wn = (wave >> 1) * 64;
  const int quad = lane >> 4, r16 = lane & 15;
  const int rowT = tid >> 3, col8 = tid & 7;

  floatx4 acc[4][4];
  #pragma unroll
  for (int i = 0; i < 4; ++i)
    #pragma unroll
    for (int j = 0; j < 4; ++j) acc[i][j] = (floatx4){0.f, 0.f, 0.f, 0.f};

  for (int kk = 0; kk < K; kk += 64) {
    __syncthreads();
    #pragma unroll
    for (int it = 0; it < 4; ++it) {
      int rr = it * 32 + rowT;
      const u16* ga = A  + (size_t)(m0 + rr) * K + kk + col8 * 8;
      const u16* gb = Bt + (size_t)(n0 + rr) * K + kk + col8 * 8;
      __builtin_amdgcn_global_load_lds((u32_as1*)ga, (u32_as3*)&lA[rr * 64 + col8 * 8], 16, 0, 0);
      __builtin_amdgcn_global_load_lds((u32_as1*)gb, (u32_as3*)&lB[rr * 64 + col8 * 8], 16, 0, 0);
    }
    __syncthreads();
    #pragma unroll
    for (int ks = 0; ks < 64; ks += 32) {
      short8 af[4], bfr[4];
      #pragma unroll
      for (int i = 0; i < 4; ++i)
        af[i] = *(const short8*)&lA[(wm + i * 16 + r16) * 64 + ks + quad * 8];
      #pragma unroll
      for (int j = 0; j < 4; ++j)
        bfr[j] = *(const short8*)&lB[(wn + j * 16 + r16) * 64 + ks + quad * 8];
      #pragma unroll
      for (int i = 0; i < 4; ++i)
        #pragma unroll
        for (int j = 0; j < 4; ++j)
          acc[i][j] = __builtin_amdgcn_mfma_f32_16x16x32_bf16(af[i], bfr[j], acc[i][j], 0, 0, 0);
    }
  }
  #pragma unroll
  for (int i = 0; i < 4; ++i) {
    #pragma unroll
    for (int rr = 0; rr < 4; ++rr) {
      int m = m0 + wm + i * 16 + quad * 4 + rr;
      const float* radd = rowAdd ? rowAdd + (size_t)(m & rowMask) * ldc : nullptr;
      #pragma unroll
      for (int j = 0; j < 4; ++j) {
        int n = n0 + wn + j * 16 + r16;
        float v = acc[i][j][rr];
        if (bias) v += bias[n];
        if (radd) v += radd[n];
        if (outBf16) ((u16*)outp)[(size_t)m * ldc + n] = f2b(v);
        else         ((float*)outp)[(size_t)m * ldc + n] = v;
      }
    }
  }
}

// --------------------------------------------- conv GEMM (circular shifts)
// h[m,n] = sum_{j,k} comb[b, (l+j-1)&4095, kc] * W1[n, j*256+kc] + conv_b[n]
__global__ __launch_bounds__(256) void gemm_conv(
    const u16* __restrict__ comb, const u16* __restrict__ W1,
    const float* __restrict__ conv_b, u16* __restrict__ h) {
  __shared__ __align__(16) u16 lA[128 * 64];
  __shared__ __align__(16) u16 lB[128 * 64];
  const int tid = threadIdx.x;
  const int m0 = blockIdx.x * 128, n0 = blockIdx.y * 128;
  const int b = m0 >> 12, l0 = m0 & 4095;
  const int wave = tid >> 6, lane = tid & 63;
  const int wm = (wave & 1) * 64, wn = (wave >> 1) * 64;
  const int quad = lane >> 4, r16 = lane & 15;
  const int rowT = tid >> 3, col8 = tid & 7;

  floatx4 acc[4][4];
  #pragma unroll
  for (int i = 0; i < 4; ++i)
    #pragma unroll
    for (int j = 0; j < 4; ++j) acc[i][j] = (floatx4){0.f, 0.f, 0.f, 0.f};

  for (int kk = 0; kk < 768; kk += 64) {
    const int j = kk >> 8, kc = kk & 255;
    __syncthreads();
    #pragma unroll
    for (int it = 0; it < 4; ++it) {
      int rr = it * 32 + rowT;
      int lsrc = (l0 + rr + j - 1 + 4096) & 4095;     // circular within batch
      const u16* ga = comb + (((size_t)(b << 12) | (size_t)lsrc) << 8) + kc + col8 * 8;
      const u16* gb = W1 + (size_t)(n0 + rr) * 768 + kk + col8 * 8;
      __builtin_amdgcn_global_load_lds((u32_as1*)ga, (u32_as3*)&lA[rr * 64 + col8 * 8], 16, 0, 0);
      __builtin_amdgcn_global_load_lds((u32_as1*)gb, (u32_as3*)&lB[rr * 64 + col8 * 8], 16, 0, 0);
    }
    __syncthreads();
    #pragma unroll
    for (int ks = 0; ks < 64; ks += 32) {
      short8 af[4], bfr[4];
      #pragma unroll
      for (int i = 0; i < 4; ++i)
        af[i] = *(const short8*)&lA[(wm + i * 16 + r16) * 64 + ks + quad * 8];
      #pragma unroll
      for (int jj = 0; jj < 4; ++jj)
        bfr[jj] = *(const short8*)&lB[(wn + jj * 16 + r16) * 64 + ks + quad * 8];
      #pragma unroll
      for (int i = 0; i < 4; ++i)
        #pragma unroll
        for (int jj = 0; jj < 4; ++jj)
          acc[i][jj] = __builtin_amdgcn_mfma_f32_16x16x32_bf16(af[i], bfr[jj], acc[i][jj], 0, 0, 0);
    }
  }
  #pragma unroll
  for (int i = 0; i < 4; ++i)
    #pragma unroll
    for (int rr = 0; rr < 4; ++rr) {
      int m = m0 + wm + i * 16 + quad * 4 + rr;
      #pragma unroll
      for (int jj = 0; jj < 4; ++jj) {
        int n = n0 + wn + jj * 16 + r16;
        h[(size_t)m * 512 + n] = f2b(acc[i][jj][rr] + conv_b[n]);
      }
    }
}

// ----------------------------------------------------- LN over D=512 rows
// one wave per row, bf16 in -> bf16 out
__global__ __launch_bounds__(256) void ln_rows(
    const u16* __restrict__ in, u16* __restrict__ out,
    const float* __restrict__ g, const float* __restrict__ bb) {
  int row = blockIdx.x * 4 + (threadIdx.x >> 6);
  int lane = threadIdx.x & 63;
  size_t base = (size_t)row * 512 + lane * 8;
  short8 raw = *(const short8*)(in + base);
  float v[8]; float s1 = 0.f, s2 = 0.f;
  #pragma unroll
  for (int e = 0; e < 8; ++e) { v[e] = b2f((u16)raw[e]); s1 += v[e]; s2 += v[e] * v[e]; }
  #pragma unroll
  for (int off = 32; off; off >>= 1) { s1 += __shfl_xor(s1, off); s2 += __shfl_xor(s2, off); }
  float mean = s1 * (1.f / 512.f);
  float inv = rsqrtf(fmaxf(s2 * (1.f / 512.f) - mean * mean, 0.f) + 1e-5f);
  short8 o;
  #pragma unroll
  for (int e = 0; e < 8; ++e) {
    int d = lane * 8 + e;
    o[e] = (short)f2b(g[d] * ((v[e] - mean) * inv) + bb[d]);
  }
  *(short8*)(out + base) = o;
}

// ------------------------------------------- per-l PE tables (fixed+learned)
__global__ __launch_bounds__(256) void pe_tables(
    const float* __restrict__ learned_pe,
    const float* __restrict__ gf, const float* __restrict__ bf_,
    const float* __restrict__ gl, const float* __restrict__ bl,
    u16* __restrict__ pf_tab, u16* __restrict__ pl_tab) {
  int row = blockIdx.x * 4 + (threadIdx.x >> 6);
  int lane = threadIdx.x & 63;
  size_t base = (size_t)row * 512 + lane * 8;
  // fixed sinusoidal
  float v[8]; float s1 = 0.f, s2 = 0.f;
  #pragma unroll
  for (int e = 0; e < 8; ++e) {
    int d = lane * 8 + e;
    int de = d & ~1;
    float div = expf((float)de * (-9.210340371976184f / 512.f));
    float ang = (float)row * div;
    v[e] = (d & 1) ? cosf(ang) : sinf(ang);
    s1 += v[e]; s2 += v[e] * v[e];
  }
  #pragma unroll
  for (int off = 32; off; off >>= 1) { s1 += __shfl_xor(s1, off); s2 += __shfl_xor(s2, off); }
  float mean = s1 * (1.f / 512.f);
  float inv = rsqrtf(fmaxf(s2 * (1.f / 512.f) - mean * mean, 0.f) + 1e-5f);
  short8 o;
  #pragma unroll
  for (int e = 0; e < 8; ++e) {
    int d = lane * 8 + e;
    o[e] = (short)f2b(gf[d] * ((v[e] - mean) * inv) + bf_[d]);
  }
  *(short8*)(pf_tab + base) = o;
  // learned
  const float4* lp = (const float4*)(learned_pe + base);   // rows 0..4095 of 5000
  float4 a = lp[0], bq = lp[1];
  float u[8] = {a.x, a.y, a.z, a.w, bq.x, bq.y, bq.z, bq.w};
  s1 = 0.f; s2 = 0.f;
  #pragma unroll
  for (int e = 0; e < 8; ++e) { s1 += u[e]; s2 += u[e] * u[e]; }
  #pragma unroll
  for (int off = 32; off; off >>= 1) { s1 += __shfl_xor(s1, off); s2 += __shfl_xor(s2, off); }
  mean = s1 * (1.f / 512.f);
  inv = rsqrtf(fmaxf(s2 * (1.f / 512.f) - mean * mean, 0.f) + 1e-5f);
  #pragma unroll
  for (int e = 0; e < 8; ++e) {
    int d = lane * 8 + e;
    o[e] = (short)f2b(gl[d] * ((u[e] - mean) * inv) + bl[d]);
  }
  *(short8*)(pl_tab + base) = o;
}

// ------------------------------------------------------------------ final
__global__ __launch_bounds__(256) void final_k(
    const u16* __restrict__ pre, const u16* __restrict__ ce,
    const u16* __restrict__ pf_tab, const u16* __restrict__ pl_tab,
    const float* __restrict__ gt, const float* __restrict__ bt,
    const float* __restrict__ wp, float* __restrict__ out) {
  int row = blockIdx.x * 4 + (threadIdx.x >> 6);
  int lane = threadIdx.x & 63;
  int l = row & 4095;
  float a0 = wp[0], a1 = wp[1], a2 = wp[2], a3 = wp[3];
  float mx = fmaxf(fmaxf(a0, a1), fmaxf(a2, a3));
  float e0 = expf(a0 - mx), e1 = expf(a1 - mx), e2 = expf(a2 - mx), e3 = expf(a3 - mx);
  float invs = 1.f / (e0 + e1 + e2 + e3);
  float w0 = e0 * invs, w1 = e1 * invs, w2 = e2 * invs, w3 = e3 * invs;

  size_t base = (size_t)row * 512 + lane * 8;
  size_t tbase = (size_t)l * 512 + lane * 8;
  short8 pr = *(const short8*)(pre + base);
  short8 cr = *(const short8*)(ce + base);
  short8 pf = *(const short8*)(pf_tab + tbase);
  short8 pl = *(const short8*)(pl_tab + tbase);

  float p[8]; float s1 = 0.f, s2 = 0.f;
  #pragma unroll
  for (int e = 0; e < 8; ++e) { p[e] = b2f((u16)pr[e]); s1 += p[e]; s2 += p[e] * p[e]; }
  #pragma unroll
  for (int off = 32; off; off >>= 1) { s1 += __shfl_xor(s1, off); s2 += __shfl_xor(s2, off); }
  float mean = s1 * (1.f / 512.f);
  float inv = rsqrtf(fmaxf(s2 * (1.f / 512.f) - mean * mean, 0.f) + 1e-5f);

  float o[8];
  #pragma unroll
  for (int e = 0; e < 8; ++e) {
    int d = lane * 8 + e;
    float pt = gt[d] * ((p[e] - mean) * inv) + bt[d];
    o[e] = w0 * b2f((u16)cr[e]) + w1 * b2f((u16)pf[e]) + w2 * b2f((u16)pl[e]) + w3 * pt;
  }
  float4* op = (float4*)(out + base);
  op[0] = make_float4(o[0], o[1], o[2], o[3]);
  op[1] = make_float4(o[4], o[5], o[6], o[7]);
}

// ---------------------------------------------------------------------------
extern "C" void kernel_launch(void* const* d_in, const int* in_sizes, int n_in,
                              void* d_out, int out_size, void* d_ws, size_t ws_size,
                              hipStream_t stream) {
  const float* x          = (const float*)d_in[0];
  const float* conv_w     = (const float*)d_in[1];
  const float* conv_b     = (const float*)d_in[2];
  const float* learned_pe = (const float*)d_in[3];
  const float* tape_pos   = (const float*)d_in[4];
  const float* tproj_w    = (const float*)d_in[5];
  const float* tproj_b    = (const float*)d_in[6];
  const float* mixer_w    = (const float*)d_in[7];
  const float* mixer_b    = (const float*)d_in[8];
  const float* g_c        = (const float*)d_in[9];
  const float* b_c        = (const float*)d_in[10];
  const float* g_f        = (const float*)d_in[11];
  const float* b_f        = (const float*)d_in[12];
  const float* g_l        = (const float*)d_in[13];
  const float* b_l        = (const float*)d_in[14];
  const float* g_t        = (const float*)d_in[15];
  const float* b_t        = (const float*)d_in[16];
  const float* wp         = (const float*)d_in[17];

  char* ws = (char*)d_ws;
  u16*  comb   = (u16*)(ws + 0);            // 32 MiB   [65536,256] bf16
  u16*  hbuf   = (u16*)(ws + 33554432);     // 64 MiB   h, then pre (reused)
  u16*  ce     = (u16*)(ws + 100663296);    // 64 MiB
  char* S      = ws + 167772160;            // small region (~23 MiB)
  u16*  W1     = (u16*)(S + 0);             // 768 KiB
  u16*  A_m1   = (u16*)(S + 786432);        // 512 KiB
  u16*  M2t    = (u16*)(S + 1310720);       // 512 KiB
  u16*  tprojT = (u16*)(S + 1835008);       // 512 KiB
  u16*  tape_bf= (u16*)(S + 2359296);       // 4 MiB
  u16*  Wf     = (u16*)(S + 6553600);       // 512 KiB
  float* ctab  = (float*)(S + 7077888);     // 8 MiB fp32 [4096,512]
  float* bias2 = (float*)(S + 15466496);    // 2 KiB
  u16*  pf_tab = (u16*)(S + 15468544);      // 4 MiB
  u16*  pl_tab = (u16*)(S + 19662848);      // 4 MiB

  prep_mats<<<12800, 256, 0, stream>>>(conv_w, mixer_w, tproj_w, tape_pos,
                                       W1, A_m1, M2t, tprojT, tape_bf);
  bias2_k<<<2, 256, 0, stream>>>(mixer_w, tproj_b, mixer_b, bias2);
  feat_kernel<<<dim3(64, 16), 256, 0, stream>>>(x, comb);
  gemm_conv<<<dim3(512, 4), 256, 0, stream>>>(comb, W1, conv_b, hbuf);
  ln_rows<<<16384, 256, 0, stream>>>(hbuf, ce, g_c, b_c);
  // Wf = M1 @ tproj_w   (bf16 out)
  gemm_bt<<<dim3(4, 4), 256, 0, stream>>>(A_m1, tprojT, Wf, 512, 512,
                                          nullptr, nullptr, 0, 1);
  // c = tape_pos @ M2^T + bias2   (fp32 out)
  gemm_bt<<<dim3(32, 4), 256, 0, stream>>>(tape_bf, M2t, ctab, 512, 512,
                                           bias2, nullptr, 0, 0);
  // pre = ce @ Wf^T + c[l]   (bf16 out, reuses hbuf)
  gemm_bt<<<dim3(512, 4), 256, 0, stream>>>(ce, Wf, hbuf, 512, 512,
                                            nullptr, ctab, 4095, 1);
  pe_tables<<<1024, 256, 0, stream>>>(learned_pe, g_f, b_f, g_l, b_l,
                                      pf_tab, pl_tab);
  final_k<<<16384, 256, 0, stream>>>(hbuf, ce, pf_tab, pl_tab, g_t, b_t,
                                     wp, (float*)d_out);
}

// Round 2
// 500.282 us; speedup vs baseline: 1.0342x; 1.0342x over previous
//
#include <hip/hip_runtime.h>
#include <stdint.h>

// ---------------------------------------------------------------------------
// DataEmbedding_ALLPE_Weighted on MI355X (gfx950)  — round 2
// B=16, L=4096, C=32, D=512.  N_tok = 65536.
//
// Round-1 diagnosis: both big GEMMs epilogue-bound (64 scalar 2B stores +
// scattered rowAdd loads per thread, MfmaUtil 10.5%), plus 110 us of
// pure-BW kernels (ln_rows, final_k) re-streaming GEMM outputs.
//
// Round-2 structure: wide-N fused GEMMs (64 rows x 512 cols per block):
//   gemm_conv_ln:    h = conv-gemm + bias -> LN -> ce          (bf16)
//   gemm_pre_final:  pre = ce@Wf^T + ctab[l] -> LN -> weighted out (fp32)
// Operand-swapped MFMA (D lane holds 4 consecutive n) -> 8B ds_write_b64
// transpose into padded LDS (stride 520), then vectorized short8/float4
// epilogue with in-kernel row LN (4 threads/row, shfl_xor 1,2).
// XOR-swizzled LDS staging (swizzle on the global-fetch side to keep
// global_load_lds's lane-linear LDS-dest constraint).
// ---------------------------------------------------------------------------

typedef unsigned short u16;
using short8  = __attribute__((ext_vector_type(8))) short;
using floatx4 = __attribute__((ext_vector_type(4))) float;
typedef __attribute__((address_space(1))) const unsigned int u32_as1;
typedef __attribute__((address_space(3))) unsigned int       u32_as3;

static __device__ __forceinline__ u16 f2b(float f) {
  unsigned u = __float_as_uint(f);
  u += 0x7FFFu + ((u >> 16) & 1u);          // RNE
  return (u16)(u >> 16);
}
static __device__ __forceinline__ float b2f(u16 h) {
  return __uint_as_float(((unsigned)h) << 16);
}

// ---------------------------------------------------------------- prep mats
__global__ __launch_bounds__(256) void prep_mats(
    const float* __restrict__ conv_w, const float* __restrict__ mixer_w,
    const float* __restrict__ tproj_w, const float* __restrict__ tape_pos,
    u16* __restrict__ W1, u16* __restrict__ A_m1, u16* __restrict__ M2t,
    u16* __restrict__ tprojT, u16* __restrict__ tape_bf) {
  int i = blockIdx.x * 256 + threadIdx.x;
  if (i < 393216) {                                    // W1: 512*768
    int d = i / 768, rem = i - d * 768;
    int j = rem >> 8, c = rem & 255;
    W1[i] = f2b(conv_w[(d * 256 + c) * 3 + j]);
  } else if (i < 393216 + 262144) {
    int k = i - 393216; int p = k >> 9, r = k & 511;
    A_m1[k] = f2b(mixer_w[p * 1024 + r]);
  } else if (i < 393216 + 524288) {
    int k = i - 393216 - 262144; int p = k >> 9, r = k & 511;
    M2t[k] = f2b(mixer_w[p * 1024 + 512 + r]);
  } else if (i < 393216 + 786432) {
    int k = i - 393216 - 524288; int q = k >> 9, r = k & 511;
    tprojT[k] = f2b(tproj_w[r * 512 + q]);
  } else if (i < 393216 + 786432 + 2097152) {
    int k = i - 393216 - 786432;
    tape_bf[k] = f2b(tape_pos[k]);
  }
}

// bias2[p] = sum_r mixer_w[p,r]*tproj_b[r] + mixer_b[p]
__global__ __launch_bounds__(256) void bias2_k(
    const float* __restrict__ mixer_w, const float* __restrict__ tproj_b,
    const float* __restrict__ mixer_b, float* __restrict__ bias2) {
  int p = blockIdx.x * 256 + threadIdx.x;
  if (p < 512) {
    float s = mixer_b[p];
    for (int r = 0; r < 512; ++r) s += mixer_w[p * 1024 + r] * tproj_b[r];
    bias2[p] = s;
  }
}

// -------------------------------------------------------------- features
__global__ __launch_bounds__(256) void feat_kernel(
    const float* __restrict__ x, u16* __restrict__ comb) {
  __shared__ float sx[87 * 32];
  const int b = blockIdx.y, l0 = blockIdx.x * 64;
  for (int idx = threadIdx.x; idx < 87 * 32; idx += 256) {
    int r = idx >> 5, c = idx & 31;
    int ls = l0 - 23 + r; if (ls < 0) ls = 0;
    sx[idx] = x[((size_t)b * 4096 + ls) * 32 + c];
  }
  __syncthreads();
  const int c = threadIdx.x & 31, lr0 = threadIdx.x >> 5;
  for (int pass = 0; pass < 8; ++pass) {
    int lr = pass * 8 + lr0;
    int l = l0 + lr;
    float w[24];
    float s = 0.f, mx = -3.4e38f, mn = 3.4e38f;
    #pragma unroll
    for (int i = 0; i < 24; ++i) {
      float v = sx[(lr + i) * 32 + c];
      w[i] = v; s += v; mx = fmaxf(mx, v); mn = fminf(mn, v);
    }
    float mean = s * (1.f / 24.f);
    float ssd = 0.f;
    #pragma unroll
    for (int i = 0; i < 24; ++i) { float d = w[i] - mean; ssd += d * d; }
    float sd = sqrtf(fmaxf(ssd, 0.f) * (1.f / 23.f));
    float xv = w[23];
    float lag3 = xv - sx[(lr + 20) * 32 + c];
    float lag5 = xv - sx[(lr + 18) * 32 + c];
    float lag7 = xv - sx[(lr + 16) * 32 + c];
    size_t base = ((size_t)b * 4096 + l) * 256 + c;
    comb[base +   0] = f2b(xv);
    comb[base +  32] = f2b(mean);
    comb[base +  64] = f2b(mx);
    comb[base +  96] = f2b(mn);
    comb[base + 128] = f2b(sd);
    comb[base + 160] = f2b(lag3);
    comb[base + 192] = f2b(lag5);
    comb[base + 224] = f2b(lag7);
  }
}

// ------------------------------------------------------- small bf16 GEMM
// (used only for Wf = M1@tproj  and  ctab = tape@M2^T + bias2; sizes tiny)
__global__ __launch_bounds__(256) void gemm_bt(
    const u16* __restrict__ A, const u16* __restrict__ Bt,
    void* __restrict__ outp, int K, int ldc,
    const float* __restrict__ bias, int outBf16) {
  __shared__ __align__(16) u16 lA[128 * 64];
  __shared__ __align__(16) u16 lB[128 * 64];
  const int tid = threadIdx.x;
  const int m0 = blockIdx.x * 128, n0 = blockIdx.y * 128;
  const int wave = tid >> 6, lane = tid & 63;
  const int wm = (wave & 1) * 64, wn = (wave >> 1) * 64;
  const int quad = lane >> 4, r16 = lane & 15;
  const int rowT = tid >> 3, col8 = tid & 7;

  floatx4 acc[4][4];
  #pragma unroll
  for (int i = 0; i < 4; ++i)
    #pragma unroll
    for (int j = 0; j < 4; ++j) acc[i][j] = (floatx4){0.f, 0.f, 0.f, 0.f};

  for (int kk = 0; kk < K; kk += 64) {
    __syncthreads();
    #pragma unroll
    for (int it = 0; it < 4; ++it) {
      int rr = it * 32 + rowT;
      const u16* ga = A  + (size_t)(m0 + rr) * K + kk + col8 * 8;
      const u16* gb = Bt + (size_t)(n0 + rr) * K + kk + col8 * 8;
      __builtin_amdgcn_global_load_lds((u32_as1*)ga, (u32_as3*)&lA[rr * 64 + col8 * 8], 16, 0, 0);
      __builtin_amdgcn_global_load_lds((u32_as1*)gb, (u32_as3*)&lB[rr * 64 + col8 * 8], 16, 0, 0);
    }
    __syncthreads();
    #pragma unroll
    for (int ks = 0; ks < 64; ks += 32) {
      short8 af[4], bfr[4];
      #pragma unroll
      for (int i = 0; i < 4; ++i)
        af[i] = *(const short8*)&lA[(wm + i * 16 + r16) * 64 + ks + quad * 8];
      #pragma unroll
      for (int j = 0; j < 4; ++j)
        bfr[j] = *(const short8*)&lB[(wn + j * 16 + r16) * 64 + ks + quad * 8];
      #pragma unroll
      for (int i = 0; i < 4; ++i)
        #pragma unroll
        for (int j = 0; j < 4; ++j)
          acc[i][j] = __builtin_amdgcn_mfma_f32_16x16x32_bf16(af[i], bfr[j], acc[i][j], 0, 0, 0);
    }
  }
  #pragma unroll
  for (int i = 0; i < 4; ++i) {
    #pragma unroll
    for (int rr = 0; rr < 4; ++rr) {
      int m = m0 + wm + i * 16 + quad * 4 + rr;
      #pragma unroll
      for (int j = 0; j < 4; ++j) {
        int n = n0 + wn + j * 16 + r16;
        float v = acc[i][j][rr];
        if (bias) v += bias[n];
        if (outBf16) ((u16*)outp)[(size_t)m * ldc + n] = f2b(v);
        else         ((float*)outp)[(size_t)m * ldc + n] = v;
      }
    }
  }
}

// ---------------------------------------------------------------------------
// Fused wide-N GEMM kernels. Block = 64 m-rows x 512 n-cols, 256 threads.
// Wave w owns n-strip [w*128, w*128+128).  Operand-swapped MFMA:
//   D = mfma(B_frag, A_frag):  lane(q,r): m = i*16 + r,  n = jj*16 + q*4 + rr
// LDS: lA [64][64] (8K) + lB [512][64] (64K), union with transpose lT
// [64][520] (66.6K). XOR swizzle: slot(row,c) holds global chunk c^(row&7).
// ---------------------------------------------------------------------------

#define STAGE_A(SRCEXPR)                                                       \
  _Pragma("unroll")                                                            \
  for (int it = 0; it < 2; ++it) {                                             \
    int id = it * 256 + tid, row = id >> 3, c = id & 7;                        \
    int cg = ((c ^ (row & 7)) << 3);                                           \
    const u16* gsrc = (SRCEXPR);                                               \
    __builtin_amdgcn_global_load_lds((u32_as1*)gsrc,                           \
        (u32_as3*)(smem + id * 16), 16, 0, 0);                                 \
  }
#define STAGE_B(SRCEXPR)                                                       \
  _Pragma("unroll")                                                            \
  for (int it = 0; it < 16; ++it) {                                            \
    int id = it * 256 + tid, row = id >> 3, c = id & 7;                        \
    int cg = ((c ^ (row & 7)) << 3);                                           \
    const u16* gsrc = (SRCEXPR);                                               \
    __builtin_amdgcn_global_load_lds((u32_as1*)gsrc,                           \
        (u32_as3*)(smem + 8192 + id * 16), 16, 0, 0);                          \
  }

// ------------------------- conv GEMM + bias + LN -> ce (bf16) -------------
__global__ __launch_bounds__(256, 2) void gemm_conv_ln(
    const u16* __restrict__ comb, const u16* __restrict__ W1,
    const float* __restrict__ conv_b, const float* __restrict__ g_c,
    const float* __restrict__ b_c, u16* __restrict__ ce) {
  __shared__ __align__(16) char smem[73728];
  __shared__ float sG[512], sB[512], sBias[512];
  u16* lA = (u16*)smem;
  u16* lB = (u16*)(smem + 8192);
  u16* lT = (u16*)smem;                       // [64][520]

  const int tid = threadIdx.x;
  if (tid < 128) {
    ((float4*)sG)[tid]    = ((const float4*)g_c)[tid];
    ((float4*)sB)[tid]    = ((const float4*)b_c)[tid];
    ((float4*)sBias)[tid] = ((const float4*)conv_b)[tid];
  }
  const int m0 = blockIdx.x * 64;
  const int b = m0 >> 12, l0 = m0 & 4095;
  const int w = tid >> 6, lane = tid & 63;
  const int quad = lane >> 4, r16 = lane & 15;

  floatx4 acc[4][8];
  #pragma unroll
  for (int i = 0; i < 4; ++i)
    #pragma unroll
    for (int jj = 0; jj < 8; ++jj) acc[i][jj] = (floatx4){0.f, 0.f, 0.f, 0.f};

  for (int kk = 0; kk < 768; kk += 64) {
    const int jsh = kk >> 8, kc = kk & 255;
    __syncthreads();
    STAGE_A(comb + (((size_t)b * 4096 + ((l0 + row + jsh - 1 + 4096) & 4095)) << 8) + kc + cg)
    STAGE_B(W1 + (size_t)row * 768 + kk + cg)
    __syncthreads();
    #pragma unroll
    for (int ks = 0; ks < 64; ks += 32) {
      short8 af[4];
      #pragma unroll
      for (int i = 0; i < 4; ++i) {
        int row = i * 16 + r16;
        af[i] = *(const short8*)&lA[row * 64 + ((((ks >> 3) + quad) ^ (row & 7)) << 3)];
      }
      #pragma unroll
      for (int jj = 0; jj < 8; ++jj) {
        int row = w * 128 + jj * 16 + r16;
        short8 bf = *(const short8*)&lB[row * 64 + ((((ks >> 3) + quad) ^ (row & 7)) << 3)];
        #pragma unroll
        for (int i = 0; i < 4; ++i)
          acc[i][jj] = __builtin_amdgcn_mfma_f32_16x16x32_bf16(bf, af[i], acc[i][jj], 0, 0, 0);
      }
    }
  }
  __syncthreads();
  // transpose to lT with conv bias added (pre-LN)
  #pragma unroll
  for (int jj = 0; jj < 8; ++jj) {
    int n = w * 128 + jj * 16 + quad * 4;
    float4 b4 = *(const float4*)&sBias[n];
    #pragma unroll
    for (int i = 0; i < 4; ++i) {
      ushort4 pk;
      pk.x = f2b(acc[i][jj][0] + b4.x);
      pk.y = f2b(acc[i][jj][1] + b4.y);
      pk.z = f2b(acc[i][jj][2] + b4.z);
      pk.w = f2b(acc[i][jj][3] + b4.w);
      *(ushort4*)(lT + (size_t)(i * 16 + r16) * 520 + n) = pk;
    }
  }
  __syncthreads();
  // LN + vectorized store: 4 threads per row, chunk-interleaved (bank-safe)
  const int orow = tid >> 2, part = tid & 3;
  float v[128];
  float s1 = 0.f, s2 = 0.f;
  #pragma unroll
  for (int k = 0; k < 16; ++k) {
    int c8 = part + k * 4;
    short8 t8 = *(const short8*)(lT + (size_t)orow * 520 + c8 * 8);
    #pragma unroll
    for (int e = 0; e < 8; ++e) {
      float f = b2f((u16)t8[e]); v[k * 8 + e] = f; s1 += f; s2 += f * f;
    }
  }
  s1 += __shfl_xor(s1, 1); s2 += __shfl_xor(s2, 1);
  s1 += __shfl_xor(s1, 2); s2 += __shfl_xor(s2, 2);
  float mean = s1 * (1.f / 512.f);
  float inv = rsqrtf(fmaxf(s2 * (1.f / 512.f) - mean * mean, 0.f) + 1e-5f);
  size_t mrow = (size_t)(m0 + orow) * 512;
  #pragma unroll
  for (int k = 0; k < 16; ++k) {
    int c8 = part + k * 4;
    float4 g0 = *(const float4*)&sG[c8 * 8], g1 = *(const float4*)&sG[c8 * 8 + 4];
    float4 bb0 = *(const float4*)&sB[c8 * 8], bb1 = *(const float4*)&sB[c8 * 8 + 4];
    float gg[8] = {g0.x, g0.y, g0.z, g0.w, g1.x, g1.y, g1.z, g1.w};
    float bv[8] = {bb0.x, bb0.y, bb0.z, bb0.w, bb1.x, bb1.y, bb1.z, bb1.w};
    short8 o;
    #pragma unroll
    for (int e = 0; e < 8; ++e)
      o[e] = (short)f2b(gg[e] * ((v[k * 8 + e] - mean) * inv) + bv[e]);
    *(short8*)(ce + mrow + c8 * 8) = o;
  }
}

// --------- pre GEMM + ctab + LN(g_t,b_t) + weighted sum -> out (fp32) -----
__global__ __launch_bounds__(256, 2) void gemm_pre_final(
    const u16* __restrict__ ceA, const u16* __restrict__ Wf,
    const u16* __restrict__ ctab_bf, const u16* __restrict__ pf_tab,
    const u16* __restrict__ pl_tab, const float* __restrict__ g_t,
    const float* __restrict__ b_t, const float* __restrict__ wp,
    float* __restrict__ out) {
  __shared__ __align__(16) char smem[73728];
  __shared__ float sG[512], sB[512];
  u16* lA = (u16*)smem;
  u16* lB = (u16*)(smem + 8192);
  u16* lT = (u16*)smem;

  const int tid = threadIdx.x;
  if (tid < 128) {
    ((float4*)sG)[tid] = ((const float4*)g_t)[tid];
    ((float4*)sB)[tid] = ((const float4*)b_t)[tid];
  }
  const int m0 = blockIdx.x * 64;
  const int l0m = m0 & 4095;
  const int w = tid >> 6, lane = tid & 63;
  const int quad = lane >> 4, r16 = lane & 15;

  floatx4 acc[4][8];
  #pragma unroll
  for (int i = 0; i < 4; ++i)
    #pragma unroll
    for (int jj = 0; jj < 8; ++jj) acc[i][jj] = (floatx4){0.f, 0.f, 0.f, 0.f};

  for (int kk = 0; kk < 512; kk += 64) {
    __syncthreads();
    STAGE_A(ceA + (size_t)(m0 + row) * 512 + kk + cg)
    STAGE_B(Wf + (size_t)row * 512 + kk + cg)
    __syncthreads();
    #pragma unroll
    for (int ks = 0; ks < 64; ks += 32) {
      short8 af[4];
      #pragma unroll
      for (int i = 0; i < 4; ++i) {
        int row = i * 16 + r16;
        af[i] = *(const short8*)&lA[row * 64 + ((((ks >> 3) + quad) ^ (row & 7)) << 3)];
      }
      #pragma unroll
      for (int jj = 0; jj < 8; ++jj) {
        int row = w * 128 + jj * 16 + r16;
        short8 bf = *(const short8*)&lB[row * 64 + ((((ks >> 3) + quad) ^ (row & 7)) << 3)];
        #pragma unroll
        for (int i = 0; i < 4; ++i)
          acc[i][jj] = __builtin_amdgcn_mfma_f32_16x16x32_bf16(bf, af[i], acc[i][jj], 0, 0, 0);
      }
    }
  }
  __syncthreads();
  #pragma unroll
  for (int jj = 0; jj < 8; ++jj) {
    int n = w * 128 + jj * 16 + quad * 4;
    #pragma unroll
    for (int i = 0; i < 4; ++i) {
      ushort4 pk;
      pk.x = f2b(acc[i][jj][0]);
      pk.y = f2b(acc[i][jj][1]);
      pk.z = f2b(acc[i][jj][2]);
      pk.w = f2b(acc[i][jj][3]);
      *(ushort4*)(lT + (size_t)(i * 16 + r16) * 520 + n) = pk;
    }
  }
  __syncthreads();
  const int orow = tid >> 2, part = tid & 3;
  const int m = m0 + orow, l = l0m + orow;
  float v[128];
  float s1 = 0.f, s2 = 0.f;
  #pragma unroll
  for (int k = 0; k < 16; ++k) {
    int c8 = part + k * 4;
    short8 t8 = *(const short8*)(lT + (size_t)orow * 520 + c8 * 8);
    short8 ct = *(const short8*)(ctab_bf + (size_t)l * 512 + c8 * 8);
    #pragma unroll
    for (int e = 0; e < 8; ++e) {
      float f = b2f((u16)t8[e]) + b2f((u16)ct[e]);
      v[k * 8 + e] = f; s1 += f; s2 += f * f;
    }
  }
  s1 += __shfl_xor(s1, 1); s2 += __shfl_xor(s2, 1);
  s1 += __shfl_xor(s1, 2); s2 += __shfl_xor(s2, 2);
  float mean = s1 * (1.f / 512.f);
  float inv = rsqrtf(fmaxf(s2 * (1.f / 512.f) - mean * mean, 0.f) + 1e-5f);

  float a0 = wp[0], a1 = wp[1], a2 = wp[2], a3 = wp[3];
  float mxw = fmaxf(fmaxf(a0, a1), fmaxf(a2, a3));
  float e0 = expf(a0 - mxw), e1 = expf(a1 - mxw), e2 = expf(a2 - mxw), e3 = expf(a3 - mxw);
  float invs = 1.f / (e0 + e1 + e2 + e3);
  float w0 = e0 * invs, w1 = e1 * invs, w2 = e2 * invs, w3 = e3 * invs;

  size_t mrow = (size_t)m * 512, lrow = (size_t)l * 512;
  #pragma unroll
  for (int k = 0; k < 16; ++k) {
    int c8 = part + k * 4;
    short8 c8v = *(const short8*)(ceA + mrow + c8 * 8);
    short8 pf  = *(const short8*)(pf_tab + lrow + c8 * 8);
    short8 pl  = *(const short8*)(pl_tab + lrow + c8 * 8);
    float4 g0 = *(const float4*)&sG[c8 * 8], g1 = *(const float4*)&sG[c8 * 8 + 4];
    float4 bb0 = *(const float4*)&sB[c8 * 8], bb1 = *(const float4*)&sB[c8 * 8 + 4];
    float gg[8] = {g0.x, g0.y, g0.z, g0.w, g1.x, g1.y, g1.z, g1.w};
    float bv[8] = {bb0.x, bb0.y, bb0.z, bb0.w, bb1.x, bb1.y, bb1.z, bb1.w};
    float o[8];
    #pragma unroll
    for (int e = 0; e < 8; ++e) {
      float pt = gg[e] * ((v[k * 8 + e] - mean) * inv) + bv[e];
      o[e] = w0 * b2f((u16)c8v[e]) + w1 * b2f((u16)pf[e]) + w2 * b2f((u16)pl[e]) + w3 * pt;
    }
    float4* op = (float4*)(out + mrow + c8 * 8);
    op[0] = make_float4(o[0], o[1], o[2], o[3]);
    op[1] = make_float4(o[4], o[5], o[6], o[7]);
  }
}

// ------------------------------------------- per-l PE tables (fixed+learned)
__global__ __launch_bounds__(256) void pe_tables(
    const float* __restrict__ learned_pe,
    const float* __restrict__ gf, const float* __restrict__ bf_,
    const float* __restrict__ gl, const float* __restrict__ bl,
    u16* __restrict__ pf_tab, u16* __restrict__ pl_tab) {
  int row = blockIdx.x * 4 + (threadIdx.x >> 6);
  int lane = threadIdx.x & 63;
  size_t base = (size_t)row * 512 + lane * 8;
  float v[8]; float s1 = 0.f, s2 = 0.f;
  #pragma unroll
  for (int e = 0; e < 8; ++e) {
    int d = lane * 8 + e;
    int de = d & ~1;
    float div = expf((float)de * (-9.210340371976184f / 512.f));
    float ang = (float)row * div;
    v[e] = (d & 1) ? cosf(ang) : sinf(ang);
    s1 += v[e]; s2 += v[e] * v[e];
  }
  #pragma unroll
  for (int off = 32; off; off >>= 1) { s1 += __shfl_xor(s1, off); s2 += __shfl_xor(s2, off); }
  float mean = s1 * (1.f / 512.f);
  float inv = rsqrtf(fmaxf(s2 * (1.f / 512.f) - mean * mean, 0.f) + 1e-5f);
  short8 o;
  #pragma unroll
  for (int e = 0; e < 8; ++e) {
    int d = lane * 8 + e;
    o[e] = (short)f2b(gf[d] * ((v[e] - mean) * inv) + bf_[d]);
  }
  *(short8*)(pf_tab + base) = o;
  const float4* lp = (const float4*)(learned_pe + base);
  float4 a = lp[0], bq = lp[1];
  float u[8] = {a.x, a.y, a.z, a.w, bq.x, bq.y, bq.z, bq.w};
  s1 = 0.f; s2 = 0.f;
  #pragma unroll
  for (int e = 0; e < 8; ++e) { s1 += u[e]; s2 += u[e] * u[e]; }
  #pragma unroll
  for (int off = 32; off; off >>= 1) { s1 += __shfl_xor(s1, off); s2 += __shfl_xor(s2, off); }
  mean = s1 * (1.f / 512.f);
  inv = rsqrtf(fmaxf(s2 * (1.f / 512.f) - mean * mean, 0.f) + 1e-5f);
  #pragma unroll
  for (int e = 0; e < 8; ++e) {
    int d = lane * 8 + e;
    o[e] = (short)f2b(gl[d] * ((u[e] - mean) * inv) + bl[d]);
  }
  *(short8*)(pl_tab + base) = o;
}

// ---------------------------------------------------------------------------
extern "C" void kernel_launch(void* const* d_in, const int* in_sizes, int n_in,
                              void* d_out, int out_size, void* d_ws, size_t ws_size,
                              hipStream_t stream) {
  const float* x          = (const float*)d_in[0];
  const float* conv_w     = (const float*)d_in[1];
  const float* conv_b     = (const float*)d_in[2];
  const float* learned_pe = (const float*)d_in[3];
  const float* tape_pos   = (const float*)d_in[4];
  const float* tproj_w    = (const float*)d_in[5];
  const float* tproj_b    = (const float*)d_in[6];
  const float* mixer_w    = (const float*)d_in[7];
  const float* mixer_b    = (const float*)d_in[8];
  const float* g_c        = (const float*)d_in[9];
  const float* b_c        = (const float*)d_in[10];
  const float* g_f        = (const float*)d_in[11];
  const float* b_f        = (const float*)d_in[12];
  const float* g_l        = (const float*)d_in[13];
  const float* b_l        = (const float*)d_in[14];
  const float* g_t        = (const float*)d_in[15];
  const float* b_t        = (const float*)d_in[16];
  const float* wp         = (const float*)d_in[17];

  char* ws = (char*)d_ws;
  u16*  comb    = (u16*)(ws + 0);             // 32 MiB
  u16*  ce      = (u16*)(ws + 33554432);      // 64 MiB
  char* S       = ws + 100663296;
  u16*  W1      = (u16*)(S + 0);              // 768 KiB
  u16*  A_m1    = (u16*)(S + 786432);         // 512 KiB
  u16*  M2t     = (u16*)(S + 1310720);        // 512 KiB
  u16*  tprojT  = (u16*)(S + 1835008);        // 512 KiB
  u16*  tape_bf = (u16*)(S + 2359296);        // 4 MiB
  u16*  Wf      = (u16*)(S + 6553600);        // 512 KiB
  u16*  ctab_bf = (u16*)(S + 7077888);        // 4 MiB
  float* bias2  = (float*)(S + 11272192);     // 2 KiB
  u16*  pf_tab  = (u16*)(S + 11274240);       // 4 MiB
  u16*  pl_tab  = (u16*)(S + 15468544);       // 4 MiB

  prep_mats<<<12800, 256, 0, stream>>>(conv_w, mixer_w, tproj_w, tape_pos,
                                       W1, A_m1, M2t, tprojT, tape_bf);
  bias2_k<<<2, 256, 0, stream>>>(mixer_w, tproj_b, mixer_b, bias2);
  feat_kernel<<<dim3(64, 16), 256, 0, stream>>>(x, comb);
  // Wf = M1 @ tproj_w   (bf16)
  gemm_bt<<<dim3(4, 4), 256, 0, stream>>>(A_m1, tprojT, Wf, 512, 512, nullptr, 1);
  // ctab = tape_pos @ M2^T + bias2   (bf16)
  gemm_bt<<<dim3(32, 4), 256, 0, stream>>>(tape_bf, M2t, ctab_bf, 512, 512, bias2, 1);
  pe_tables<<<1024, 256, 0, stream>>>(learned_pe, g_f, b_f, g_l, b_l, pf_tab, pl_tab);
  // fused conv + LN -> ce
  gemm_conv_ln<<<1024, 256, 0, stream>>>(comb, W1, conv_b, g_c, b_c, ce);
  // fused pre + LN + weighted sum -> out
  gemm_pre_final<<<1024, 256, 0, stream>>>(ce, Wf, ctab_bf, pf_tab, pl_tab,
                                           g_t, b_t, wp, (float*)d_out);
}

// Round 3
// 391.532 us; speedup vs baseline: 1.3215x; 1.2778x over previous
//
#include <hip/hip_runtime.h>
#include <stdint.h>

// ---------------------------------------------------------------------------
// DataEmbedding_ALLPE_Weighted on MI355X (gfx950)  — round 3
//
// Round-2 diagnosis: float v[128] per-thread epilogue arrays in both fused
// GEMM kernels spilled to scratch (WRITE_SIZE 330 MB vs 134 MB ideal =
// +134 MB scratch write + read-back). Fix: two-pass LN epilogue over LDS —
// pass 1 accumulates sum/sumsq streaming from LDS, pass 2 re-reads LDS and
// applies LN + store. No per-thread arrays anywhere.
// ---------------------------------------------------------------------------

typedef unsigned short u16;
using short8  = __attribute__((ext_vector_type(8))) short;
using floatx4 = __attribute__((ext_vector_type(4))) float;
typedef __attribute__((address_space(1))) const unsigned int u32_as1;
typedef __attribute__((address_space(3))) unsigned int       u32_as3;

static __device__ __forceinline__ u16 f2b(float f) {
  unsigned u = __float_as_uint(f);
  u += 0x7FFFu + ((u >> 16) & 1u);          // RNE
  return (u16)(u >> 16);
}
static __device__ __forceinline__ float b2f(u16 h) {
  return __uint_as_float(((unsigned)h) << 16);
}

// ---------------------------------------------------------------- prep mats
__global__ __launch_bounds__(256) void prep_mats(
    const float* __restrict__ conv_w, const float* __restrict__ mixer_w,
    const float* __restrict__ tproj_w, const float* __restrict__ tape_pos,
    u16* __restrict__ W1, u16* __restrict__ A_m1, u16* __restrict__ M2t,
    u16* __restrict__ tprojT, u16* __restrict__ tape_bf) {
  int i = blockIdx.x * 256 + threadIdx.x;
  if (i < 393216) {                                    // W1: 512*768
    int d = i / 768, rem = i - d * 768;
    int j = rem >> 8, c = rem & 255;
    W1[i] = f2b(conv_w[(d * 256 + c) * 3 + j]);
  } else if (i < 393216 + 262144) {
    int k = i - 393216; int p = k >> 9, r = k & 511;
    A_m1[k] = f2b(mixer_w[p * 1024 + r]);
  } else if (i < 393216 + 524288) {
    int k = i - 393216 - 262144; int p = k >> 9, r = k & 511;
    M2t[k] = f2b(mixer_w[p * 1024 + 512 + r]);
  } else if (i < 393216 + 786432) {
    int k = i - 393216 - 524288; int q = k >> 9, r = k & 511;
    tprojT[k] = f2b(tproj_w[r * 512 + q]);
  } else if (i < 393216 + 786432 + 2097152) {
    int k = i - 393216 - 786432;
    tape_bf[k] = f2b(tape_pos[k]);
  }
}

// bias2[p] = sum_r mixer_w[p,r]*tproj_b[r] + mixer_b[p]
__global__ __launch_bounds__(256) void bias2_k(
    const float* __restrict__ mixer_w, const float* __restrict__ tproj_b,
    const float* __restrict__ mixer_b, float* __restrict__ bias2) {
  int p = blockIdx.x * 256 + threadIdx.x;
  if (p < 512) {
    float s = mixer_b[p];
    for (int r = 0; r < 512; ++r) s += mixer_w[p * 1024 + r] * tproj_b[r];
    bias2[p] = s;
  }
}

// -------------------------------------------------------------- features
__global__ __launch_bounds__(256) void feat_kernel(
    const float* __restrict__ x, u16* __restrict__ comb) {
  __shared__ float sx[87 * 32];
  const int b = blockIdx.y, l0 = blockIdx.x * 64;
  for (int idx = threadIdx.x; idx < 87 * 32; idx += 256) {
    int r = idx >> 5, c = idx & 31;
    int ls = l0 - 23 + r; if (ls < 0) ls = 0;
    sx[idx] = x[((size_t)b * 4096 + ls) * 32 + c];
  }
  __syncthreads();
  const int c = threadIdx.x & 31, lr0 = threadIdx.x >> 5;
  for (int pass = 0; pass < 8; ++pass) {
    int lr = pass * 8 + lr0;
    int l = l0 + lr;
    float w[24];
    float s = 0.f, mx = -3.4e38f, mn = 3.4e38f;
    #pragma unroll
    for (int i = 0; i < 24; ++i) {
      float v = sx[(lr + i) * 32 + c];
      w[i] = v; s += v; mx = fmaxf(mx, v); mn = fminf(mn, v);
    }
    float mean = s * (1.f / 24.f);
    float ssd = 0.f;
    #pragma unroll
    for (int i = 0; i < 24; ++i) { float d = w[i] - mean; ssd += d * d; }
    float sd = sqrtf(fmaxf(ssd, 0.f) * (1.f / 23.f));
    float xv = w[23];
    float lag3 = xv - sx[(lr + 20) * 32 + c];
    float lag5 = xv - sx[(lr + 18) * 32 + c];
    float lag7 = xv - sx[(lr + 16) * 32 + c];
    size_t base = ((size_t)b * 4096 + l) * 256 + c;
    comb[base +   0] = f2b(xv);
    comb[base +  32] = f2b(mean);
    comb[base +  64] = f2b(mx);
    comb[base +  96] = f2b(mn);
    comb[base + 128] = f2b(sd);
    comb[base + 160] = f2b(lag3);
    comb[base + 192] = f2b(lag5);
    comb[base + 224] = f2b(lag7);
  }
}

// ------------------------------------------------------- small bf16 GEMM
__global__ __launch_bounds__(256) void gemm_bt(
    const u16* __restrict__ A, const u16* __restrict__ Bt,
    void* __restrict__ outp, int K, int ldc,
    const float* __restrict__ bias, int outBf16) {
  __shared__ __align__(16) u16 lA[128 * 64];
  __shared__ __align__(16) u16 lB[128 * 64];
  const int tid = threadIdx.x;
  const int m0 = blockIdx.x * 128, n0 = blockIdx.y * 128;
  const int wave = tid >> 6, lane = tid & 63;
  const int wm = (wave & 1) * 64, wn = (wave >> 1) * 64;
  const int quad = lane >> 4, r16 = lane & 15;
  const int rowT = tid >> 3, col8 = tid & 7;

  floatx4 acc[4][4];
  #pragma unroll
  for (int i = 0; i < 4; ++i)
    #pragma unroll
    for (int j = 0; j < 4; ++j) acc[i][j] = (floatx4){0.f, 0.f, 0.f, 0.f};

  for (int kk = 0; kk < K; kk += 64) {
    __syncthreads();
    #pragma unroll
    for (int it = 0; it < 4; ++it) {
      int rr = it * 32 + rowT;
      const u16* ga = A  + (size_t)(m0 + rr) * K + kk + col8 * 8;
      const u16* gb = Bt + (size_t)(n0 + rr) * K + kk + col8 * 8;
      __builtin_amdgcn_global_load_lds((u32_as1*)ga, (u32_as3*)&lA[rr * 64 + col8 * 8], 16, 0, 0);
      __builtin_amdgcn_global_load_lds((u32_as1*)gb, (u32_as3*)&lB[rr * 64 + col8 * 8], 16, 0, 0);
    }
    __syncthreads();
    #pragma unroll
    for (int ks = 0; ks < 64; ks += 32) {
      short8 af[4], bfr[4];
      #pragma unroll
      for (int i = 0; i < 4; ++i)
        af[i] = *(const short8*)&lA[(wm + i * 16 + r16) * 64 + ks + quad * 8];
      #pragma unroll
      for (int j = 0; j < 4; ++j)
        bfr[j] = *(const short8*)&lB[(wn + j * 16 + r16) * 64 + ks + quad * 8];
      #pragma unroll
      for (int i = 0; i < 4; ++i)
        #pragma unroll
        for (int j = 0; j < 4; ++j)
          acc[i][j] = __builtin_amdgcn_mfma_f32_16x16x32_bf16(af[i], bfr[j], acc[i][j], 0, 0, 0);
    }
  }
  #pragma unroll
  for (int i = 0; i < 4; ++i) {
    #pragma unroll
    for (int rr = 0; rr < 4; ++rr) {
      int m = m0 + wm + i * 16 + quad * 4 + rr;
      #pragma unroll
      for (int j = 0; j < 4; ++j) {
        int n = n0 + wn + j * 16 + r16;
        float v = acc[i][j][rr];
        if (bias) v += bias[n];
        if (outBf16) ((u16*)outp)[(size_t)m * ldc + n] = f2b(v);
        else         ((float*)outp)[(size_t)m * ldc + n] = v;
      }
    }
  }
}

// ---------------------------------------------------------------------------
// Fused wide-N GEMM kernels. Block = 64 m-rows x 512 n-cols, 256 threads.
// Wave w owns n-strip [w*128, w*128+128).  Operand-swapped MFMA:
//   D = mfma(B_frag, A_frag):  lane(q,r): m = i*16 + r,  n = jj*16 + q*4 + rr
// LDS: lA [64][64] (8K) + lB [512][64] (64K), union with transpose lT
// [64][520] (66.6K). XOR swizzle: slot(row,c) holds global chunk c^(row&7).
// Epilogue is TWO-PASS over LDS (no per-thread v[128] array -> no scratch
// spills; round-2 lesson).
// ---------------------------------------------------------------------------

#define STAGE_A(SRCEXPR)                                                       \
  _Pragma("unroll")                                                            \
  for (int it = 0; it < 2; ++it) {                                             \
    int id = it * 256 + tid, row = id >> 3, c = id & 7;                        \
    int cg = ((c ^ (row & 7)) << 3);                                           \
    const u16* gsrc = (SRCEXPR);                                               \
    __builtin_amdgcn_global_load_lds((u32_as1*)gsrc,                           \
        (u32_as3*)(smem + id * 16), 16, 0, 0);                                 \
  }
#define STAGE_B(SRCEXPR)                                                       \
  _Pragma("unroll")                                                            \
  for (int it = 0; it < 16; ++it) {                                            \
    int id = it * 256 + tid, row = id >> 3, c = id & 7;                        \
    int cg = ((c ^ (row & 7)) << 3);                                           \
    const u16* gsrc = (SRCEXPR);                                               \
    __builtin_amdgcn_global_load_lds((u32_as1*)gsrc,                           \
        (u32_as3*)(smem + 8192 + id * 16), 16, 0, 0);                          \
  }

// ------------------------- conv GEMM + bias + LN -> ce (bf16) -------------
__global__ __launch_bounds__(256, 2) void gemm_conv_ln(
    const u16* __restrict__ comb, const u16* __restrict__ W1,
    const float* __restrict__ conv_b, const float* __restrict__ g_c,
    const float* __restrict__ b_c, u16* __restrict__ ce) {
  __shared__ __align__(16) char smem[73728];
  __shared__ float sG[512], sB[512], sBias[512];
  u16* lA = (u16*)smem;
  u16* lB = (u16*)(smem + 8192);
  u16* lT = (u16*)smem;                       // [64][520]

  const int tid = threadIdx.x;
  if (tid < 128) {
    ((float4*)sG)[tid]    = ((const float4*)g_c)[tid];
    ((float4*)sB)[tid]    = ((const float4*)b_c)[tid];
    ((float4*)sBias)[tid] = ((const float4*)conv_b)[tid];
  }
  const int m0 = blockIdx.x * 64;
  const int b = m0 >> 12, l0 = m0 & 4095;
  const int w = tid >> 6, lane = tid & 63;
  const int quad = lane >> 4, r16 = lane & 15;

  floatx4 acc[4][8];
  #pragma unroll
  for (int i = 0; i < 4; ++i)
    #pragma unroll
    for (int jj = 0; jj < 8; ++jj) acc[i][jj] = (floatx4){0.f, 0.f, 0.f, 0.f};

  for (int kk = 0; kk < 768; kk += 64) {
    const int jsh = kk >> 8, kc = kk & 255;
    __syncthreads();
    STAGE_A(comb + (((size_t)b * 4096 + ((l0 + row + jsh - 1 + 4096) & 4095)) << 8) + kc + cg)
    STAGE_B(W1 + (size_t)row * 768 + kk + cg)
    __syncthreads();
    #pragma unroll
    for (int ks = 0; ks < 64; ks += 32) {
      short8 af[4];
      #pragma unroll
      for (int i = 0; i < 4; ++i) {
        int row = i * 16 + r16;
        af[i] = *(const short8*)&lA[row * 64 + ((((ks >> 3) + quad) ^ (row & 7)) << 3)];
      }
      #pragma unroll
      for (int jj = 0; jj < 8; ++jj) {
        int row = w * 128 + jj * 16 + r16;
        short8 bf = *(const short8*)&lB[row * 64 + ((((ks >> 3) + quad) ^ (row & 7)) << 3)];
        #pragma unroll
        for (int i = 0; i < 4; ++i)
          acc[i][jj] = __builtin_amdgcn_mfma_f32_16x16x32_bf16(bf, af[i], acc[i][jj], 0, 0, 0);
      }
    }
  }
  __syncthreads();
  // transpose to lT with conv bias added (pre-LN)
  #pragma unroll
  for (int jj = 0; jj < 8; ++jj) {
    int n = w * 128 + jj * 16 + quad * 4;
    float4 b4 = *(const float4*)&sBias[n];
    #pragma unroll
    for (int i = 0; i < 4; ++i) {
      ushort4 pk;
      pk.x = f2b(acc[i][jj][0] + b4.x);
      pk.y = f2b(acc[i][jj][1] + b4.y);
      pk.z = f2b(acc[i][jj][2] + b4.z);
      pk.w = f2b(acc[i][jj][3] + b4.w);
      *(ushort4*)(lT + (size_t)(i * 16 + r16) * 520 + n) = pk;
    }
  }
  __syncthreads();
  // two-pass LN (no per-thread array -> no scratch)
  const int orow = tid >> 2, part = tid & 3;
  const u16* rowp = lT + (size_t)orow * 520;
  float s1 = 0.f, s2 = 0.f;
  #pragma unroll
  for (int k = 0; k < 16; ++k) {
    short8 t8 = *(const short8*)(rowp + (part + k * 4) * 8);
    #pragma unroll
    for (int e = 0; e < 8; ++e) {
      float f = b2f((u16)t8[e]); s1 += f; s2 += f * f;
    }
  }
  s1 += __shfl_xor(s1, 1); s2 += __shfl_xor(s2, 1);
  s1 += __shfl_xor(s1, 2); s2 += __shfl_xor(s2, 2);
  float mean = s1 * (1.f / 512.f);
  float inv = rsqrtf(fmaxf(s2 * (1.f / 512.f) - mean * mean, 0.f) + 1e-5f);
  size_t mrow = (size_t)(m0 + orow) * 512;
  #pragma unroll
  for (int k = 0; k < 16; ++k) {
    int c8 = part + k * 4;
    short8 t8 = *(const short8*)(rowp + c8 * 8);
    short8 o;
    #pragma unroll
    for (int e = 0; e < 8; ++e) {
      int d = c8 * 8 + e;
      o[e] = (short)f2b(sG[d] * ((b2f((u16)t8[e]) - mean) * inv) + sB[d]);
    }
    *(short8*)(ce + mrow + c8 * 8) = o;
  }
}

// --------- pre GEMM + ctab + LN(g_t,b_t) + weighted sum -> out (fp32) -----
__global__ __launch_bounds__(256, 2) void gemm_pre_final(
    const u16* __restrict__ ceA, const u16* __restrict__ Wf,
    const u16* __restrict__ ctab_bf, const u16* __restrict__ pf_tab,
    const u16* __restrict__ pl_tab, const float* __restrict__ g_t,
    const float* __restrict__ b_t, const float* __restrict__ wp,
    float* __restrict__ out) {
  __shared__ __align__(16) char smem[73728];
  __shared__ float sG[512], sB[512];
  u16* lA = (u16*)smem;
  u16* lB = (u16*)(smem + 8192);
  u16* lT = (u16*)smem;

  const int tid = threadIdx.x;
  if (tid < 128) {
    ((float4*)sG)[tid] = ((const float4*)g_t)[tid];
    ((float4*)sB)[tid] = ((const float4*)b_t)[tid];
  }
  const int m0 = blockIdx.x * 64;
  const int l0m = m0 & 4095;
  const int w = tid >> 6, lane = tid & 63;
  const int quad = lane >> 4, r16 = lane & 15;

  floatx4 acc[4][8];
  #pragma unroll
  for (int i = 0; i < 4; ++i)
    #pragma unroll
    for (int jj = 0; jj < 8; ++jj) acc[i][jj] = (floatx4){0.f, 0.f, 0.f, 0.f};

  for (int kk = 0; kk < 512; kk += 64) {
    __syncthreads();
    STAGE_A(ceA + (size_t)(m0 + row) * 512 + kk + cg)
    STAGE_B(Wf + (size_t)row * 512 + kk + cg)
    __syncthreads();
    #pragma unroll
    for (int ks = 0; ks < 64; ks += 32) {
      short8 af[4];
      #pragma unroll
      for (int i = 0; i < 4; ++i) {
        int row = i * 16 + r16;
        af[i] = *(const short8*)&lA[row * 64 + ((((ks >> 3) + quad) ^ (row & 7)) << 3)];
      }
      #pragma unroll
      for (int jj = 0; jj < 8; ++jj) {
        int row = w * 128 + jj * 16 + r16;
        short8 bf = *(const short8*)&lB[row * 64 + ((((ks >> 3) + quad) ^ (row & 7)) << 3)];
        #pragma unroll
        for (int i = 0; i < 4; ++i)
          acc[i][jj] = __builtin_amdgcn_mfma_f32_16x16x32_bf16(bf, af[i], acc[i][jj], 0, 0, 0);
      }
    }
  }
  __syncthreads();
  #pragma unroll
  for (int jj = 0; jj < 8; ++jj) {
    int n = w * 128 + jj * 16 + quad * 4;
    #pragma unroll
    for (int i = 0; i < 4; ++i) {
      ushort4 pk;
      pk.x = f2b(acc[i][jj][0]);
      pk.y = f2b(acc[i][jj][1]);
      pk.z = f2b(acc[i][jj][2]);
      pk.w = f2b(acc[i][jj][3]);
      *(ushort4*)(lT + (size_t)(i * 16 + r16) * 520 + n) = pk;
    }
  }
  __syncthreads();
  const int orow = tid >> 2, part = tid & 3;
  const int m = m0 + orow, l = l0m + orow;
  const u16* rowp = lT + (size_t)orow * 520;
  const size_t lrow = (size_t)l * 512, mrow = (size_t)m * 512;
  // pass 1: sum/sumsq of (pre + ctab)
  float s1 = 0.f, s2 = 0.f;
  #pragma unroll
  for (int k = 0; k < 16; ++k) {
    int c8 = part + k * 4;
    short8 t8 = *(const short8*)(rowp + c8 * 8);
    short8 ct = *(const short8*)(ctab_bf + lrow + c8 * 8);
    #pragma unroll
    for (int e = 0; e < 8; ++e) {
      float f = b2f((u16)t8[e]) + b2f((u16)ct[e]);
      s1 += f; s2 += f * f;
    }
  }
  s1 += __shfl_xor(s1, 1); s2 += __shfl_xor(s2, 1);
  s1 += __shfl_xor(s1, 2); s2 += __shfl_xor(s2, 2);
  float mean = s1 * (1.f / 512.f);
  float inv = rsqrtf(fmaxf(s2 * (1.f / 512.f) - mean * mean, 0.f) + 1e-5f);

  float a0 = wp[0], a1 = wp[1], a2 = wp[2], a3 = wp[3];
  float mxw = fmaxf(fmaxf(a0, a1), fmaxf(a2, a3));
  float e0 = expf(a0 - mxw), e1 = expf(a1 - mxw), e2 = expf(a2 - mxw), e3 = expf(a3 - mxw);
  float invs = 1.f / (e0 + e1 + e2 + e3);
  float w0 = e0 * invs, w1 = e1 * invs, w2 = e2 * invs, w3 = e3 * invs;

  // pass 2: re-read LDS + ctab, add weighted ce/pf/pl, store fp32
  #pragma unroll
  for (int k = 0; k < 16; ++k) {
    int c8 = part + k * 4;
    short8 t8  = *(const short8*)(rowp + c8 * 8);
    short8 ct  = *(const short8*)(ctab_bf + lrow + c8 * 8);
    short8 c8v = *(const short8*)(ceA + mrow + c8 * 8);
    short8 pf  = *(const short8*)(pf_tab + lrow + c8 * 8);
    short8 pl  = *(const short8*)(pl_tab + lrow + c8 * 8);
    float o[8];
    #pragma unroll
    for (int e = 0; e < 8; ++e) {
      int d = c8 * 8 + e;
      float f = b2f((u16)t8[e]) + b2f((u16)ct[e]);
      float pt = sG[d] * ((f - mean) * inv) + sB[d];
      o[e] = w0 * b2f((u16)c8v[e]) + w1 * b2f((u16)pf[e]) + w2 * b2f((u16)pl[e]) + w3 * pt;
    }
    float4* op = (float4*)(out + mrow + c8 * 8);
    op[0] = make_float4(o[0], o[1], o[2], o[3]);
    op[1] = make_float4(o[4], o[5], o[6], o[7]);
  }
}

// ------------------------------------------- per-l PE tables (fixed+learned)
__global__ __launch_bounds__(256) void pe_tables(
    const float* __restrict__ learned_pe,
    const float* __restrict__ gf, const float* __restrict__ bf_,
    const float* __restrict__ gl, const float* __restrict__ bl,
    u16* __restrict__ pf_tab, u16* __restrict__ pl_tab) {
  int row = blockIdx.x * 4 + (threadIdx.x >> 6);
  int lane = threadIdx.x & 63;
  size_t base = (size_t)row * 512 + lane * 8;
  float v[8]; float s1 = 0.f, s2 = 0.f;
  #pragma unroll
  for (int e = 0; e < 8; ++e) {
    int d = lane * 8 + e;
    int de = d & ~1;
    float div = expf((float)de * (-9.210340371976184f / 512.f));
    float ang = (float)row * div;
    v[e] = (d & 1) ? cosf(ang) : sinf(ang);
    s1 += v[e]; s2 += v[e] * v[e];
  }
  #pragma unroll
  for (int off = 32; off; off >>= 1) { s1 += __shfl_xor(s1, off); s2 += __shfl_xor(s2, off); }
  float mean = s1 * (1.f / 512.f);
  float inv = rsqrtf(fmaxf(s2 * (1.f / 512.f) - mean * mean, 0.f) + 1e-5f);
  short8 o;
  #pragma unroll
  for (int e = 0; e < 8; ++e) {
    int d = lane * 8 + e;
    o[e] = (short)f2b(gf[d] * ((v[e] - mean) * inv) + bf_[d]);
  }
  *(short8*)(pf_tab + base) = o;
  const float4* lp = (const float4*)(learned_pe + base);
  float4 a = lp[0], bq = lp[1];
  float u[8] = {a.x, a.y, a.z, a.w, bq.x, bq.y, bq.z, bq.w};
  s1 = 0.f; s2 = 0.f;
  #pragma unroll
  for (int e = 0; e < 8; ++e) { s1 += u[e]; s2 += u[e] * u[e]; }
  #pragma unroll
  for (int off = 32; off; off >>= 1) { s1 += __shfl_xor(s1, off); s2 += __shfl_xor(s2, off); }
  mean = s1 * (1.f / 512.f);
  inv = rsqrtf(fmaxf(s2 * (1.f / 512.f) - mean * mean, 0.f) + 1e-5f);
  #pragma unroll
  for (int e = 0; e < 8; ++e) {
    int d = lane * 8 + e;
    o[e] = (short)f2b(gl[d] * ((u[e] - mean) * inv) + bl[d]);
  }
  *(short8*)(pl_tab + base) = o;
}

// ---------------------------------------------------------------------------
extern "C" void kernel_launch(void* const* d_in, const int* in_sizes, int n_in,
                              void* d_out, int out_size, void* d_ws, size_t ws_size,
                              hipStream_t stream) {
  const float* x          = (const float*)d_in[0];
  const float* conv_w     = (const float*)d_in[1];
  const float* conv_b     = (const float*)d_in[2];
  const float* learned_pe = (const float*)d_in[3];
  const float* tape_pos   = (const float*)d_in[4];
  const float* tproj_w    = (const float*)d_in[5];
  const float* tproj_b    = (const float*)d_in[6];
  const float* mixer_w    = (const float*)d_in[7];
  const float* mixer_b    = (const float*)d_in[8];
  const float* g_c        = (const float*)d_in[9];
  const float* b_c        = (const float*)d_in[10];
  const float* g_f        = (const float*)d_in[11];
  const float* b_f        = (const float*)d_in[12];
  const float* g_l        = (const float*)d_in[13];
  const float* b_l        = (const float*)d_in[14];
  const float* g_t        = (const float*)d_in[15];
  const float* b_t        = (const float*)d_in[16];
  const float* wp         = (const float*)d_in[17];

  char* ws = (char*)d_ws;
  u16*  comb    = (u16*)(ws + 0);             // 32 MiB
  u16*  ce      = (u16*)(ws + 33554432);      // 64 MiB
  char* S       = ws + 100663296;
  u16*  W1      = (u16*)(S + 0);              // 768 KiB
  u16*  A_m1    = (u16*)(S + 786432);         // 512 KiB
  u16*  M2t     = (u16*)(S + 1310720);        // 512 KiB
  u16*  tprojT  = (u16*)(S + 1835008);        // 512 KiB
  u16*  tape_bf = (u16*)(S + 2359296);        // 4 MiB
  u16*  Wf      = (u16*)(S + 6553600);        // 512 KiB
  u16*  ctab_bf = (u16*)(S + 7077888);        // 4 MiB
  float* bias2  = (float*)(S + 11272192);     // 2 KiB
  u16*  pf_tab  = (u16*)(S + 11274240);       // 4 MiB
  u16*  pl_tab  = (u16*)(S + 15468544);       // 4 MiB

  prep_mats<<<12800, 256, 0, stream>>>(conv_w, mixer_w, tproj_w, tape_pos,
                                       W1, A_m1, M2t, tprojT, tape_bf);
  bias2_k<<<2, 256, 0, stream>>>(mixer_w, tproj_b, mixer_b, bias2);
  feat_kernel<<<dim3(64, 16), 256, 0, stream>>>(x, comb);
  // Wf = M1 @ tproj_w   (bf16)
  gemm_bt<<<dim3(4, 4), 256, 0, stream>>>(A_m1, tprojT, Wf, 512, 512, nullptr, 1);
  // ctab = tape_pos @ M2^T + bias2   (bf16)
  gemm_bt<<<dim3(32, 4), 256, 0, stream>>>(tape_bf, M2t, ctab_bf, 512, 512, bias2, 1);
  pe_tables<<<1024, 256, 0, stream>>>(learned_pe, g_f, b_f, g_l, b_l, pf_tab, pl_tab);
  // fused conv + LN -> ce
  gemm_conv_ln<<<1024, 256, 0, stream>>>(comb, W1, conv_b, g_c, b_c, ce);
  // fused pre + LN + weighted sum -> out
  gemm_pre_final<<<1024, 256, 0, stream>>>(ce, Wf, ctab_bf, pf_tab, pl_tab,
                                           g_t, b_t, wp, (float*)d_out);
}